// Round 14
// baseline (1816.370 us; speedup 1.0000x reference)
//
#include <hip/hip_runtime.h>
#include <hip/hip_cooperative_groups.h>
#include <cmath>

namespace cg = cooperative_groups;

#define B_   8
#define CI_  3
#define CM_  21
#define H_   128
#define W_   128
#define K_   32
#define PAD_ 8
#define PW_  144
#define PH_  144
#define NC_  3   // mask channels per block (21 = 7 groups of 3)

typedef float f4 __attribute__((ext_vector_type(4)));
typedef _Float16 h4 __attribute__((ext_vector_type(4)));
typedef _Float16 h8v __attribute__((ext_vector_type(8)));

struct PosSoft { float v[K_]; };

// shifted fp16 window: elements [S .. S+3] of concat(A,B); half-select perm.
template<int S>
__device__ __forceinline__ h4 shwh(h4 A, h4 B) {
  return __builtin_shufflevector(A, B, S, S + 1, S + 2, S + 3);
}

// raw h4 global load (8 B, full-line coalesced)
__device__ __forceinline__ h4 lda(const _Float16* p, int off) {
  return *reinterpret_cast<const h4*>(p + off);
}

// ---------------------------------------------------------------------------
// Phase A: per-pixel affinity (softmax over K=32) + constant position term.
// SINGLE-PASS register-cached gather. Output: aff[b][i][k][j], fp16.
// ---------------------------------------------------------------------------
__global__ __launch_bounds__(128) void aff_kernel(const float* __restrict__ imgs,
                                                  _Float16* __restrict__ aff,
                                                  PosSoft ps) {
  constexpr int OI[8] = {-1,-1,-1, 0, 0, 1, 1, 1};
  constexpr int OJ[8] = {-1, 0, 1,-1, 1,-1, 0, 1};
  const int j = threadIdx.x;
  const int i = blockIdx.x;
  const int b = blockIdx.y;
  const float* img = imgs + (size_t)b * CI_ * H_ * W_;

  float ctr0 = img[0 * H_ * W_ + i * W_ + j];
  float ctr1 = img[1 * H_ * W_ + i * W_ + j];
  float ctr2 = img[2 * H_ * W_ + i * W_ + j];

  float v0[K_], v1[K_], v2[K_];
  float s0 = 0.f, s1 = 0.f, s2 = 0.f;
  float q0 = 0.f, q1 = 0.f, q2 = 0.f;
#pragma unroll
  for (int k = 0; k < K_; ++k) {
    const int d  = 1 << (k >> 3);
    const int ci = min(max(i + OI[k & 7] * d, 0), H_ - 1);
    const int cj = min(max(j + OJ[k & 7] * d, 0), W_ - 1);
    float a = img[0 * H_ * W_ + ci * W_ + cj];
    float c = img[1 * H_ * W_ + ci * W_ + cj];
    float e = img[2 * H_ * W_ + ci * W_ + cj];
    v0[k] = a; s0 += a; q0 += a * a;
    v1[k] = c; s1 += c; q1 += c * c;
    v2[k] = e; s2 += e; q2 += e * e;
  }

  float mean0 = s0 * (1.f / K_), mean1 = s1 * (1.f / K_), mean2 = s2 * (1.f / K_);
  float var0 = fmaxf((q0 - (float)K_ * mean0 * mean0) * (1.f / (K_ - 1)), 0.f);
  float var1 = fmaxf((q1 - (float)K_ * mean1 * mean1) * (1.f / (K_ - 1)), 0.f);
  float var2 = fmaxf((q2 - (float)K_ * mean2 * mean2) * (1.f / (K_ - 1)), 0.f);
  float inv0 = 1.f / ((sqrtf(var0) + 1e-8f) * 0.3f);
  float inv1 = 1.f / ((sqrtf(var1) + 1e-8f) * 0.3f);
  float inv2 = 1.f / ((sqrtf(var2) + 1e-8f) * 0.3f);

  float araw[K_];
#pragma unroll
  for (int k = 0; k < K_; ++k) {
    float d0 = fabsf(v0[k] - ctr0) * inv0;
    float d1 = fabsf(v1[k] - ctr1) * inv1;
    float d2 = fabsf(v2[k] - ctr2) * inv2;
    araw[k] = -(d0 * d0 + d1 * d1 + d2 * d2) * (1.f / CI_);
  }

  float m = araw[0];
#pragma unroll
  for (int k = 1; k < K_; ++k) m = fmaxf(m, araw[k]);
  float sum = 0.f;
#pragma unroll
  for (int k = 0; k < K_; ++k) { float e = __expf(araw[k] - m); araw[k] = e; sum += e; }
  const float rs = 1.f / sum;

  _Float16* ap = aff + ((size_t)(b * H_ + i) * K_) * W_ + j;
#pragma unroll
  for (int k = 0; k < K_; ++k) ap[k * W_] = (_Float16)(araw[k] * rs + ps.v[k]);
}

// ---------------------------------------------------------------------------
// Pad masks into edge-replicated 144x144 fp16 planes. One h4 slot per thread.
// ---------------------------------------------------------------------------
__global__ void pad_kernel(const float* __restrict__ src, _Float16* __restrict__ dst,
                           int total4) {
  int idx = blockIdx.x * blockDim.x + threadIdx.x;
  if (idx >= total4) return;
  int q  = idx % (PW_ / 4);
  int t  = idx / (PW_ / 4);
  int pi = t % PH_;
  int p  = t / PH_;
  int i = min(max(pi - PAD_, 0), H_ - 1);
  const float* srow = src + (size_t)p * (H_ * W_) + i * W_;
  h4 o;
#pragma unroll
  for (int e = 0; e < 4; ++e) {
    int j = min(max(q * 4 + e - PAD_, 0), W_ - 1);
    o[e] = (_Float16)srow[j];
  }
  *reinterpret_cast<h4*>(dst + (size_t)p * (PH_ * PW_) + pi * PW_ + q * 4) = o;
}

// ---------------------------------------------------------------------------
// Shared iter tap macros (TR=4 geometry). sm[] holds padded rows i0..i0+19
// x 144 cols x 3 channels, fp16. ds_read_b64 taps, v_pk_fma_f16 math.
// ---------------------------------------------------------------------------
#define LX(C, DR, CO) (lb + ((C) * 2880 + ((DR) + 8) * 144 + ((CO) + 8)))
#define LDSH(IDX) (*reinterpret_cast<const h4*>(&sm[(IDX)]))

#define HCH(C, ACC) do {                                                       \
    h4 m2 = LDSH(LX(C, 0, -8)), m1 = LDSH(LX(C, 0, -4));                       \
    h4 c0 = LDSH(LX(C, 0, 0)),  c1 = LDSH(LX(C, 0, 4));                        \
    h4 c2 = LDSH(LX(C, 0, 8));                                                 \
    ACC += a03 * shwh<3>(m1, c0) + a04 * shwh<1>(c0, c1);                      \
    ACC += a13 * shwh<2>(m1, c0) + a14 * shwh<2>(c0, c1);                      \
    ACC += a23 * m1 + a24 * c1;                                                \
    ACC += a33 * m2 + a34 * c2;                                                \
  } while (0)

#define VCHS(D, SM, A0, A1, A2, A5, A6, A7, C, ACC) do {                       \
    h4 ua = LDSH(LX(C, -(D), -4)), ub = LDSH(LX(C, -(D), 0));                  \
    h4 uc = LDSH(LX(C, -(D), 4));                                              \
    ACC += A0 * shwh<SM>(ua, ub) + A1 * ub + A2 * shwh<D>(ub, uc);             \
    h4 da = LDSH(LX(C, (D), -4)), db = LDSH(LX(C, (D), 0));                    \
    h4 dc = LDSH(LX(C, (D), 4));                                               \
    ACC += A5 * shwh<SM>(da, db) + A6 * db + A7 * shwh<D>(db, dc);             \
  } while (0)

#define VCH4(A0, A1, A2, A5, A6, A7, C, ACC) do {                              \
    h4 ua = LDSH(LX(C, -4, -4)), ub = LDSH(LX(C, -4, 0)), uc = LDSH(LX(C, -4, 4)); \
    ACC += A0 * ua + A1 * ub + A2 * uc;                                        \
    h4 da = LDSH(LX(C, 4, -4)), db = LDSH(LX(C, 4, 0)), dc = LDSH(LX(C, 4, 4)); \
    ACC += A5 * da + A6 * db + A7 * dc;                                        \
  } while (0)

#define VCH8(A0, A1, A2, A5, A6, A7, C, ACC) do {                              \
    h4 ua = LDSH(LX(C, -8, -8)), ub = LDSH(LX(C, -8, 0)), uc = LDSH(LX(C, -8, 8)); \
    ACC += A0 * ua + A1 * ub + A2 * uc;                                        \
    h4 da = LDSH(LX(C, 8, -8)), db = LDSH(LX(C, 8, 0)), dc = LDSH(LX(C, 8, 8)); \
    ACC += A5 * da + A6 * db + A7 * dc;                                        \
  } while (0)

// aff prefetch into 32 named h4 regs (k = dil*8 + slot)
#define AFF_PREFETCH                                                           \
  h4 a00 = lda(ab,  0 * W_), a01 = lda(ab,  1 * W_), a02 = lda(ab,  2 * W_),   \
     a03 = lda(ab,  3 * W_), a04 = lda(ab,  4 * W_), a05 = lda(ab,  5 * W_),   \
     a06 = lda(ab,  6 * W_), a07 = lda(ab,  7 * W_);                           \
  h4 a10 = lda(ab,  8 * W_), a11 = lda(ab,  9 * W_), a12 = lda(ab, 10 * W_),   \
     a13 = lda(ab, 11 * W_), a14 = lda(ab, 12 * W_), a15 = lda(ab, 13 * W_),   \
     a16 = lda(ab, 14 * W_), a17 = lda(ab, 15 * W_);                           \
  h4 a20 = lda(ab, 16 * W_), a21 = lda(ab, 17 * W_), a22 = lda(ab, 18 * W_),   \
     a23 = lda(ab, 19 * W_), a24 = lda(ab, 20 * W_), a25 = lda(ab, 21 * W_),   \
     a26 = lda(ab, 22 * W_), a27 = lda(ab, 23 * W_);                           \
  h4 a30 = lda(ab, 24 * W_), a31 = lda(ab, 25 * W_), a32 = lda(ab, 26 * W_),   \
     a33 = lda(ab, 27 * W_), a34 = lda(ab, 28 * W_), a35 = lda(ab, 29 * W_),   \
     a36 = lda(ab, 30 * W_), a37 = lda(ab, 31 * W_);

#define COMPUTE_ACCS                                                           \
  h4 acc0 = (h4){0, 0, 0, 0};                                                  \
  h4 acc1 = (h4){0, 0, 0, 0};                                                  \
  h4 acc2 = (h4){0, 0, 0, 0};                                                  \
  HCH(0, acc0); HCH(1, acc1); HCH(2, acc2);                                    \
  VCHS(1, 3, a00, a01, a02, a05, a06, a07, 0, acc0);                           \
  VCHS(1, 3, a00, a01, a02, a05, a06, a07, 1, acc1);                           \
  VCHS(1, 3, a00, a01, a02, a05, a06, a07, 2, acc2);                           \
  VCHS(2, 2, a10, a11, a12, a15, a16, a17, 0, acc0);                           \
  VCHS(2, 2, a10, a11, a12, a15, a16, a17, 1, acc1);                           \
  VCHS(2, 2, a10, a11, a12, a15, a16, a17, 2, acc2);                           \
  VCH4(a20, a21, a22, a25, a26, a27, 0, acc0);                                 \
  VCH4(a20, a21, a22, a25, a26, a27, 1, acc1);                                 \
  VCH4(a20, a21, a22, a25, a26, a27, 2, acc2);                                 \
  VCH8(a30, a31, a32, a35, a36, a37, 0, acc0);                                 \
  VCH8(a30, a31, a32, a35, a36, a37, 1, acc1);                                 \
  VCH8(a30, a31, a32, a35, a36, a37, 2, acc2);

#define EPI_PADDED(DSTP) do {                                                  \
    _Float16* d0 = (DSTP) + (size_t)(b * CM_ + c0) * CHP;                      \
    _Float16* d1 = d0 + CHP;                                                   \
    _Float16* d2 = d0 + 2 * CHP;                                               \
    const int pr = i + PAD_;                                                   \
    const int r0 = (i == 0)      ? 0         : pr;                             \
    const int r1 = (i == H_ - 1) ? (PH_ - 1) : pr;                             \
    for (int r = r0; r <= r1; ++r) {                                           \
      _Float16* row0 = d0 + r * PW_;                                           \
      _Float16* row1 = d1 + r * PW_;                                           \
      _Float16* row2 = d2 + r * PW_;                                           \
      *reinterpret_cast<h4*>(row0 + PAD_ + j0) = acc0;                         \
      *reinterpret_cast<h4*>(row1 + PAD_ + j0) = acc1;                         \
      *reinterpret_cast<h4*>(row2 + PAD_ + j0) = acc2;                         \
      if (qx == 0) {                                                           \
        h4 s0 = (h4){acc0.x, acc0.x, acc0.x, acc0.x};                          \
        h4 s1 = (h4){acc1.x, acc1.x, acc1.x, acc1.x};                          \
        h4 s2 = (h4){acc2.x, acc2.x, acc2.x, acc2.x};                          \
        *reinterpret_cast<h4*>(row0) = s0; *reinterpret_cast<h4*>(row0 + 4) = s0; \
        *reinterpret_cast<h4*>(row1) = s1; *reinterpret_cast<h4*>(row1 + 4) = s1; \
        *reinterpret_cast<h4*>(row2) = s2; *reinterpret_cast<h4*>(row2 + 4) = s2; \
      }                                                                        \
      if (qx == 31) {                                                          \
        h4 s0 = (h4){acc0.w, acc0.w, acc0.w, acc0.w};                          \
        h4 s1 = (h4){acc1.w, acc1.w, acc1.w, acc1.w};                          \
        h4 s2 = (h4){acc2.w, acc2.w, acc2.w, acc2.w};                          \
        *reinterpret_cast<h4*>(row0 + PW_ - 8) = s0; *reinterpret_cast<h4*>(row0 + PW_ - 4) = s0; \
        *reinterpret_cast<h4*>(row1 + PW_ - 8) = s1; *reinterpret_cast<h4*>(row1 + PW_ - 4) = s1; \
        *reinterpret_cast<h4*>(row2 + PW_ - 8) = s2; *reinterpret_cast<h4*>(row2 + PW_ - 4) = s2; \
      }                                                                        \
    }                                                                          \
  } while (0)

#define STAGE_SM(SRCP) do {                                                    \
    const _Float16* pl = (SRCP) + (size_t)(b * CM_ + c0) * CHP + (size_t)i0 * PW_; \
    for (int s = tid; s < 1080; s += 128) {                                    \
      int c = s / 360;                                                         \
      int r = s - c * 360;                                                     \
      h8v v = *reinterpret_cast<const h8v*>(pl + (size_t)c * CHP + r * 8);     \
      *reinterpret_cast<h8v*>(&sm[c * 2880 + r * 8]) = v;                      \
    }                                                                          \
  } while (0)

// ---------------------------------------------------------------------------
// PERSISTENT cooperative kernel: all 10 propagation iterations in one
// dispatch. Aff fragments live in registers across iterations (loaded once);
// grid.sync() between iterations. Grid 1792 = exactly 7 blocks/CU.
// ---------------------------------------------------------------------------
__global__ __launch_bounds__(128, 4) void iter_coop(_Float16* __restrict__ P0b,
                                                    _Float16* __restrict__ P1b,
                                                    const _Float16* __restrict__ aff,
                                                    float* __restrict__ out) {
  cg::grid_group gg = cg::this_grid();
  __shared__ _Float16 sm[NC_ * 20 * PW_];   // 17280 B

  const int bid  = blockIdx.x;
  const int b    = bid & 7;
  const int t    = bid >> 3;
  const int grp  = t % 7;
  const int tile = t / 7;

  const int tid = threadIdx.x;
  const int qx  = tid & 31;
  const int j0  = qx * 4;
  const int tr  = tid >> 5;
  const int i   = tile * 4 + tr;
  const int i0  = tile * 4;
  const int c0  = grp * NC_;
  const int lb  = tr * PW_ + j0;

  constexpr int CHP = PH_ * PW_;

  // iteration-invariant: aff fragments, loaded ONCE for all 10 iterations
  const _Float16* ab = aff + ((size_t)(b * H_ + i) * K_) * W_ + j0;
  AFF_PREFETCH

#pragma unroll 1
  for (int it = 0; it < 10; ++it) {
    const _Float16* srcp = (it & 1) ? P1b : P0b;
    STAGE_SM(srcp);
    __syncthreads();

    COMPUTE_ACCS

    if (it < 9) {
      _Float16* dstp = (it & 1) ? P0b : P1b;
      EPI_PADDED(dstp);
      gg.sync();                       // all writes visible before next stage
    } else {
      float* dc = out + (size_t)(b * CM_ + c0) * (H_ * W_) + (size_t)i * W_ + j0;
      *reinterpret_cast<f4*>(dc)                 = __builtin_convertvector(acc0, f4);
      *reinterpret_cast<f4*>(dc + (H_ * W_))     = __builtin_convertvector(acc1, f4);
      *reinterpret_cast<f4*>(dc + 2 * (H_ * W_)) = __builtin_convertvector(acc2, f4);
    }
  }
}

// ---------------------------------------------------------------------------
// Fallback single-iteration kernel (R12 structure) if cooperative launch
// is unavailable. PADOUT=1 -> fp16 padded dst; PADOUT=0 -> f32 out.
// ---------------------------------------------------------------------------
template <int PADOUT>
__global__ __launch_bounds__(128, 3) void iter_kernel(const _Float16* __restrict__ src,
                                                      const _Float16* __restrict__ aff,
                                                      void* __restrict__ dstv) {
  __shared__ _Float16 sm[NC_ * 20 * PW_];

  const int bid  = blockIdx.x;
  const int b    = bid & 7;
  const int t    = bid >> 3;
  const int grp  = t % 7;
  const int tile = t / 7;

  const int tid = threadIdx.x;
  const int qx  = tid & 31;
  const int j0  = qx * 4;
  const int tr  = tid >> 5;
  const int i   = tile * 4 + tr;
  const int i0  = tile * 4;
  const int c0  = grp * NC_;
  const int lb  = tr * PW_ + j0;

  constexpr int CHP = PH_ * PW_;

  const _Float16* ab = aff + ((size_t)(b * H_ + i) * K_) * W_ + j0;
  AFF_PREFETCH

  STAGE_SM(src);
  __syncthreads();

  COMPUTE_ACCS

  if (PADOUT) {
    EPI_PADDED((_Float16*)dstv);
  } else {
    float* dc = (float*)dstv + (size_t)(b * CM_ + c0) * (H_ * W_) + (size_t)i * W_ + j0;
    *reinterpret_cast<f4*>(dc)                 = __builtin_convertvector(acc0, f4);
    *reinterpret_cast<f4*>(dc + (H_ * W_))     = __builtin_convertvector(acc1, f4);
    *reinterpret_cast<f4*>(dc + 2 * (H_ * W_)) = __builtin_convertvector(acc2, f4);
  }
}

// ---------------------------------------------------------------------------
extern "C" void kernel_launch(void* const* d_in, const int* in_sizes, int n_in,
                              void* d_out, int out_size, void* d_ws, size_t ws_size,
                              hipStream_t stream) {
  const float* imgs  = (const float*)d_in[0];
  const float* masks = (const float*)d_in[1];
  float* out = (float*)d_out;

  char* ws = (char*)d_ws;
  const size_t affBytes = (size_t)B_ * K_ * H_ * W_ * sizeof(_Float16);     // 8.4 MB
  const size_t padBytes = (size_t)B_ * CM_ * PH_ * PW_ * sizeof(_Float16);  // 7.0 MB
  _Float16* aff = (_Float16*)ws;
  _Float16* P0  = (_Float16*)(ws + affBytes);
  _Float16* P1  = (_Float16*)(ws + affBytes + padBytes);

  PosSoft ps;
  {
    const double pv[8] = {1.4142135623730951, 1.0, 1.4142135623730951, 1.0,
                          1.0, 1.4142135623730951, 1.0, 1.4142135623730951};
    double pos[K_];
    for (int di = 0; di < 4; ++di) {
      double d = (double)(1 << di);
      for (int o = 0; o < 8; ++o) pos[di * 8 + o] = pv[o] * d;
    }
    double mean = 0; for (int k = 0; k < K_; ++k) mean += pos[k]; mean /= K_;
    double var = 0;  for (int k = 0; k < K_; ++k) { double dd = pos[k] - mean; var += dd * dd; }
    var /= (K_ - 1);
    double sd = sqrt(var);
    double pa[K_]; double m = -1e300;
    for (int k = 0; k < K_; ++k) {
      double r = pos[k] / ((sd + 1e-8) * 0.3);
      pa[k] = -(r * r);
      if (pa[k] > m) m = pa[k];
    }
    double es = 0; for (int k = 0; k < K_; ++k) { pa[k] = exp(pa[k] - m); es += pa[k]; }
    for (int k = 0; k < K_; ++k) ps.v[k] = (float)(0.01 * pa[k] / es);
  }

  aff_kernel<<<dim3(H_, B_), 128, 0, stream>>>(imgs, aff, ps);

  const int total4 = B_ * CM_ * PH_ * (PW_ / 4);
  pad_kernel<<<(total4 + 255) / 256, 256, 0, stream>>>(masks, P0, total4);

  const int nblk = B_ * 7 * (H_ / 4);   // 1792 = exactly 7 blocks/CU

  void* args[] = {(void*)&P0, (void*)&P1, (void*)&aff, (void*)&out};
  hipError_t ce = hipLaunchCooperativeKernel((const void*)iter_coop,
                                             dim3(nblk), dim3(128),
                                             args, 0, stream);
  if (ce != hipSuccess) {
    // fallback: proven 10-dispatch ping-pong path
    _Float16* s = P0;
    _Float16* d = P1;
    for (int it = 0; it < 9; ++it) {
      iter_kernel<1><<<nblk, 128, 0, stream>>>(s, aff, (void*)d);
      _Float16* tm = s; s = d; d = tm;
    }
    iter_kernel<0><<<nblk, 128, 0, stream>>>(s, aff, (void*)out);
  }
}

// Round 15
// 128.254 us; speedup vs baseline: 14.1623x; 14.1623x over previous
//
#include <hip/hip_runtime.h>
#include <cmath>

#define B_   8
#define CI_  3
#define CM_  21
#define H_   128
#define W_   128
#define K_   32
#define PAD_ 8
#define PW_  144
#define PH_  144
#define NC_  3    // mask channels per block in iter kernel (21 = 7 groups of 3)
#define TR_  8    // output rows per iter block
#define SR_  24   // staged rows per block (full +-8 halo)

typedef float f4 __attribute__((ext_vector_type(4)));
typedef _Float16 h4 __attribute__((ext_vector_type(4)));
typedef _Float16 h8v __attribute__((ext_vector_type(8)));

struct PosSoft { float v[K_]; };

// shifted fp16 window: elements [S .. S+3] of concat(A,B); half-select perm.
template<int S>
__device__ __forceinline__ h4 shwh(h4 A, h4 B) {
  return __builtin_shufflevector(A, B, S, S + 1, S + 2, S + 3);
}

// raw h4 global load (8 B, full-line coalesced)
__device__ __forceinline__ h4 lda(const _Float16* p, int off) {
  return *reinterpret_cast<const h4*>(p + off);
}

// ---------------------------------------------------------------------------
// Phase A: per-pixel affinity (softmax over K=32) + constant position term.
// SINGLE-PASS register-cached gather. Output: aff[b][i][k][j], fp16.
// ---------------------------------------------------------------------------
__global__ __launch_bounds__(128) void aff_kernel(const float* __restrict__ imgs,
                                                  _Float16* __restrict__ aff,
                                                  PosSoft ps) {
  constexpr int OI[8] = {-1,-1,-1, 0, 0, 1, 1, 1};
  constexpr int OJ[8] = {-1, 0, 1,-1, 1,-1, 0, 1};
  const int j = threadIdx.x;
  const int i = blockIdx.x;
  const int b = blockIdx.y;
  const float* img = imgs + (size_t)b * CI_ * H_ * W_;

  float ctr0 = img[0 * H_ * W_ + i * W_ + j];
  float ctr1 = img[1 * H_ * W_ + i * W_ + j];
  float ctr2 = img[2 * H_ * W_ + i * W_ + j];

  float v0[K_], v1[K_], v2[K_];
  float s0 = 0.f, s1 = 0.f, s2 = 0.f;
  float q0 = 0.f, q1 = 0.f, q2 = 0.f;
#pragma unroll
  for (int k = 0; k < K_; ++k) {
    const int d  = 1 << (k >> 3);
    const int ci = min(max(i + OI[k & 7] * d, 0), H_ - 1);
    const int cj = min(max(j + OJ[k & 7] * d, 0), W_ - 1);
    float a = img[0 * H_ * W_ + ci * W_ + cj];
    float c = img[1 * H_ * W_ + ci * W_ + cj];
    float e = img[2 * H_ * W_ + ci * W_ + cj];
    v0[k] = a; s0 += a; q0 += a * a;
    v1[k] = c; s1 += c; q1 += c * c;
    v2[k] = e; s2 += e; q2 += e * e;
  }

  float mean0 = s0 * (1.f / K_), mean1 = s1 * (1.f / K_), mean2 = s2 * (1.f / K_);
  float var0 = fmaxf((q0 - (float)K_ * mean0 * mean0) * (1.f / (K_ - 1)), 0.f);
  float var1 = fmaxf((q1 - (float)K_ * mean1 * mean1) * (1.f / (K_ - 1)), 0.f);
  float var2 = fmaxf((q2 - (float)K_ * mean2 * mean2) * (1.f / (K_ - 1)), 0.f);
  float inv0 = 1.f / ((sqrtf(var0) + 1e-8f) * 0.3f);
  float inv1 = 1.f / ((sqrtf(var1) + 1e-8f) * 0.3f);
  float inv2 = 1.f / ((sqrtf(var2) + 1e-8f) * 0.3f);

  float araw[K_];
#pragma unroll
  for (int k = 0; k < K_; ++k) {
    float d0 = fabsf(v0[k] - ctr0) * inv0;
    float d1 = fabsf(v1[k] - ctr1) * inv1;
    float d2 = fabsf(v2[k] - ctr2) * inv2;
    araw[k] = -(d0 * d0 + d1 * d1 + d2 * d2) * (1.f / CI_);
  }

  float m = araw[0];
#pragma unroll
  for (int k = 1; k < K_; ++k) m = fmaxf(m, araw[k]);
  float sum = 0.f;
#pragma unroll
  for (int k = 0; k < K_; ++k) { float e = __expf(araw[k] - m); araw[k] = e; sum += e; }
  const float rs = 1.f / sum;

  _Float16* ap = aff + ((size_t)(b * H_ + i) * K_) * W_ + j;
#pragma unroll
  for (int k = 0; k < K_; ++k) ap[k * W_] = (_Float16)(araw[k] * rs + ps.v[k]);
}

// ---------------------------------------------------------------------------
// Pad masks into edge-replicated 144x144 fp16 planes. One h4 slot per thread.
// ---------------------------------------------------------------------------
__global__ void pad_kernel(const float* __restrict__ src, _Float16* __restrict__ dst,
                           int total4) {
  int idx = blockIdx.x * blockDim.x + threadIdx.x;
  if (idx >= total4) return;
  int q  = idx % (PW_ / 4);
  int t  = idx / (PW_ / 4);
  int pi = t % PH_;
  int p  = t / PH_;
  int i = min(max(pi - PAD_, 0), H_ - 1);
  const float* srow = src + (size_t)p * (H_ * W_) + i * W_;
  h4 o;
#pragma unroll
  for (int e = 0; e < 4; ++e) {
    int j = min(max(q * 4 + e - PAD_, 0), W_ - 1);
    o[e] = (_Float16)srow[j];
  }
  *reinterpret_cast<h4*>(dst + (size_t)p * (PH_ * PW_) + pi * PW_ + q * 4) = o;
}

// ---------------------------------------------------------------------------
// iter_kernel tap macros, fp16-packed LDS edition. sm[] holds padded rows
// i0..i0+23 (image rows i0-8..i0+15) x 144 cols x 3 channels. Taps are
// ds_read_b64 (h4) at compile-time-folded offsets; math is v_pk_fma_f16
// with h4 accumulators. Aff fragments a00..a37 prefetched pre-staging.
// ---------------------------------------------------------------------------
#define LX(C, DR, CO) (lb + ((C) * (SR_ * PW_) + ((DR) + 8) * PW_ + ((CO) + 8)))
#define LDSH(IDX) (*reinterpret_cast<const h4*>(&sm[(IDX)]))

// horizontal taps, all 4 dilations, one channel (center row dr=0)
#define HCH(C, ACC) do {                                                       \
    h4 m2 = LDSH(LX(C, 0, -8)), m1 = LDSH(LX(C, 0, -4));                       \
    h4 c0 = LDSH(LX(C, 0, 0)),  c1 = LDSH(LX(C, 0, 4));                        \
    h4 c2 = LDSH(LX(C, 0, 8));                                                 \
    ACC += a03 * shwh<3>(m1, c0) + a04 * shwh<1>(c0, c1);                      \
    ACC += a13 * shwh<2>(m1, c0) + a14 * shwh<2>(c0, c1);                      \
    ACC += a23 * m1 + a24 * c1;                                                \
    ACC += a33 * m2 + a34 * c2;                                                \
  } while (0)

// vertical+diagonal taps, shifted dilation D in {1,2}, SM = 4-D
#define VCHS(D, SM, A0, A1, A2, A5, A6, A7, C, ACC) do {                       \
    h4 ua = LDSH(LX(C, -(D), -4)), ub = LDSH(LX(C, -(D), 0));                  \
    h4 uc = LDSH(LX(C, -(D), 4));                                              \
    ACC += A0 * shwh<SM>(ua, ub) + A1 * ub + A2 * shwh<D>(ub, uc);             \
    h4 da = LDSH(LX(C, (D), -4)), db = LDSH(LX(C, (D), 0));                    \
    h4 dc = LDSH(LX(C, (D), 4));                                               \
    ACC += A5 * shwh<SM>(da, db) + A6 * db + A7 * shwh<D>(db, dc);             \
  } while (0)

// vertical+diagonal taps, aligned dilation 4
#define VCH4(A0, A1, A2, A5, A6, A7, C, ACC) do {                              \
    h4 ua = LDSH(LX(C, -4, -4)), ub = LDSH(LX(C, -4, 0)), uc = LDSH(LX(C, -4, 4)); \
    ACC += A0 * ua + A1 * ub + A2 * uc;                                        \
    h4 da = LDSH(LX(C, 4, -4)), db = LDSH(LX(C, 4, 0)), dc = LDSH(LX(C, 4, 4)); \
    ACC += A5 * da + A6 * db + A7 * dc;                                        \
  } while (0)

// vertical+diagonal taps, aligned dilation 8
#define VCH8(A0, A1, A2, A5, A6, A7, C, ACC) do {                              \
    h4 ua = LDSH(LX(C, -8, -8)), ub = LDSH(LX(C, -8, 0)), uc = LDSH(LX(C, -8, 8)); \
    ACC += A0 * ua + A1 * ub + A2 * uc;                                        \
    h4 da = LDSH(LX(C, 8, -8)), db = LDSH(LX(C, 8, 0)), dc = LDSH(LX(C, 8, 8)); \
    ACC += A5 * da + A6 * db + A7 * dc;                                        \
  } while (0)

// ---------------------------------------------------------------------------
// Propagation step. Block 256 thr = 8 rows x 32 col-quads (4 px/thread),
// 3 channels. Grid 896, XCD-pinned: b = bid & 7. fp16 planes + fp16 aff,
// fp16 packed accumulation. Aff prefetched pre-staging; mask taps from LDS.
// Staging amplification 3x (24 rows per 8 output rows).
// ---------------------------------------------------------------------------
template <int PADOUT>
__global__ __launch_bounds__(256, 3) void iter_kernel(const _Float16* __restrict__ src,
                                                      const _Float16* __restrict__ aff,
                                                      void* __restrict__ dstv) {
  __shared__ _Float16 sm[NC_ * SR_ * PW_];   // 3 ch x 24 rows x 144 = 20736 B

  const int bid  = blockIdx.x;
  const int b    = bid & 7;
  const int t    = bid >> 3;
  const int grp  = t % 7;
  const int tile = t / 7;            // 0..15

  const int tid = threadIdx.x;
  const int qx  = tid & 31;
  const int j0  = qx * 4;
  const int tr  = tid >> 5;          // 0..7
  const int i   = tile * TR_ + tr;
  const int i0  = tile * TR_;
  const int c0  = grp * NC_;

  constexpr int CHP = PH_ * PW_;

  // ---- aff prefetch: 32 named h4 regs, issued before staging loads so they
  // fly under the staging latency + barrier. k = dil*8 + slot.
  const _Float16* ab = aff + ((size_t)(b * H_ + i) * K_) * W_ + j0;
  h4 a00 = lda(ab,  0 * W_), a01 = lda(ab,  1 * W_), a02 = lda(ab,  2 * W_),
     a03 = lda(ab,  3 * W_), a04 = lda(ab,  4 * W_), a05 = lda(ab,  5 * W_),
     a06 = lda(ab,  6 * W_), a07 = lda(ab,  7 * W_);
  h4 a10 = lda(ab,  8 * W_), a11 = lda(ab,  9 * W_), a12 = lda(ab, 10 * W_),
     a13 = lda(ab, 11 * W_), a14 = lda(ab, 12 * W_), a15 = lda(ab, 13 * W_),
     a16 = lda(ab, 14 * W_), a17 = lda(ab, 15 * W_);
  h4 a20 = lda(ab, 16 * W_), a21 = lda(ab, 17 * W_), a22 = lda(ab, 18 * W_),
     a23 = lda(ab, 19 * W_), a24 = lda(ab, 20 * W_), a25 = lda(ab, 21 * W_),
     a26 = lda(ab, 22 * W_), a27 = lda(ab, 23 * W_);
  h4 a30 = lda(ab, 24 * W_), a31 = lda(ab, 25 * W_), a32 = lda(ab, 26 * W_),
     a33 = lda(ab, 27 * W_), a34 = lda(ab, 28 * W_), a35 = lda(ab, 29 * W_),
     a36 = lda(ab, 30 * W_), a37 = lda(ab, 31 * W_);

  // ---- stage: padded rows [i0 .. i0+23] (image rows i0-8..i0+15), 3 ch.
  // 16B chunks: 432 per channel (24*144/8), 1296 total; contiguous + aligned.
  {
    const _Float16* pl = src + (size_t)(b * CM_ + c0) * CHP + (size_t)i0 * PW_;
    for (int s = tid; s < NC_ * (SR_ * PW_ / 8); s += 256) {
      int c = s / (SR_ * PW_ / 8);
      int r = s - c * (SR_ * PW_ / 8);
      h8v v = *reinterpret_cast<const h8v*>(pl + (size_t)c * CHP + r * 8);
      *reinterpret_cast<h8v*>(&sm[c * (SR_ * PW_) + r * 8]) = v;
    }
  }
  __syncthreads();

  const int lb = tr * PW_ + j0;      // runtime part of LDS tap index

  h4 acc0 = (h4){0, 0, 0, 0};
  h4 acc1 = (h4){0, 0, 0, 0};
  h4 acc2 = (h4){0, 0, 0, 0};

  // ---- horizontal pass (all dilations) then vertical per dilation
  HCH(0, acc0); HCH(1, acc1); HCH(2, acc2);

  VCHS(1, 3, a00, a01, a02, a05, a06, a07, 0, acc0);
  VCHS(1, 3, a00, a01, a02, a05, a06, a07, 1, acc1);
  VCHS(1, 3, a00, a01, a02, a05, a06, a07, 2, acc2);

  VCHS(2, 2, a10, a11, a12, a15, a16, a17, 0, acc0);
  VCHS(2, 2, a10, a11, a12, a15, a16, a17, 1, acc1);
  VCHS(2, 2, a10, a11, a12, a15, a16, a17, 2, acc2);

  VCH4(a20, a21, a22, a25, a26, a27, 0, acc0);
  VCH4(a20, a21, a22, a25, a26, a27, 1, acc1);
  VCH4(a20, a21, a22, a25, a26, a27, 2, acc2);

  VCH8(a30, a31, a32, a35, a36, a37, 0, acc0);
  VCH8(a30, a31, a32, a35, a36, a37, 1, acc1);
  VCH8(a30, a31, a32, a35, a36, a37, 2, acc2);

  // ---- epilogue
  if (PADOUT) {
    _Float16* d0 = (_Float16*)dstv + (size_t)(b * CM_ + c0) * CHP;
    _Float16* d1 = d0 + CHP;
    _Float16* d2 = d0 + 2 * CHP;
    const int pr = i + PAD_;
    const int r0 = (i == 0)      ? 0         : pr;
    const int r1 = (i == H_ - 1) ? (PH_ - 1) : pr;
    for (int r = r0; r <= r1; ++r) {
      _Float16* row0 = d0 + r * PW_;
      _Float16* row1 = d1 + r * PW_;
      _Float16* row2 = d2 + r * PW_;
      *reinterpret_cast<h4*>(row0 + PAD_ + j0) = acc0;
      *reinterpret_cast<h4*>(row1 + PAD_ + j0) = acc1;
      *reinterpret_cast<h4*>(row2 + PAD_ + j0) = acc2;
      if (qx == 0) {
        h4 s0 = (h4){acc0.x, acc0.x, acc0.x, acc0.x};
        h4 s1 = (h4){acc1.x, acc1.x, acc1.x, acc1.x};
        h4 s2 = (h4){acc2.x, acc2.x, acc2.x, acc2.x};
        *reinterpret_cast<h4*>(row0) = s0; *reinterpret_cast<h4*>(row0 + 4) = s0;
        *reinterpret_cast<h4*>(row1) = s1; *reinterpret_cast<h4*>(row1 + 4) = s1;
        *reinterpret_cast<h4*>(row2) = s2; *reinterpret_cast<h4*>(row2 + 4) = s2;
      }
      if (qx == 31) {
        h4 s0 = (h4){acc0.w, acc0.w, acc0.w, acc0.w};
        h4 s1 = (h4){acc1.w, acc1.w, acc1.w, acc1.w};
        h4 s2 = (h4){acc2.w, acc2.w, acc2.w, acc2.w};
        *reinterpret_cast<h4*>(row0 + PW_ - 8) = s0; *reinterpret_cast<h4*>(row0 + PW_ - 4) = s0;
        *reinterpret_cast<h4*>(row1 + PW_ - 8) = s1; *reinterpret_cast<h4*>(row1 + PW_ - 4) = s1;
        *reinterpret_cast<h4*>(row2 + PW_ - 8) = s2; *reinterpret_cast<h4*>(row2 + PW_ - 4) = s2;
      }
    }
  } else {
    float* dc = (float*)dstv + (size_t)(b * CM_ + c0) * (H_ * W_) + (size_t)i * W_ + j0;
    *reinterpret_cast<f4*>(dc)                 = __builtin_convertvector(acc0, f4);
    *reinterpret_cast<f4*>(dc + (H_ * W_))     = __builtin_convertvector(acc1, f4);
    *reinterpret_cast<f4*>(dc + 2 * (H_ * W_)) = __builtin_convertvector(acc2, f4);
  }
}

// ---------------------------------------------------------------------------
extern "C" void kernel_launch(void* const* d_in, const int* in_sizes, int n_in,
                              void* d_out, int out_size, void* d_ws, size_t ws_size,
                              hipStream_t stream) {
  const float* imgs  = (const float*)d_in[0];
  const float* masks = (const float*)d_in[1];
  float* out = (float*)d_out;

  char* ws = (char*)d_ws;
  const size_t affBytes = (size_t)B_ * K_ * H_ * W_ * sizeof(_Float16);     // 8.4 MB
  const size_t padBytes = (size_t)B_ * CM_ * PH_ * PW_ * sizeof(_Float16);  // 7.0 MB
  _Float16* aff = (_Float16*)ws;
  _Float16* P0  = (_Float16*)(ws + affBytes);
  _Float16* P1  = (_Float16*)(ws + affBytes + padBytes);

  PosSoft ps;
  {
    const double pv[8] = {1.4142135623730951, 1.0, 1.4142135623730951, 1.0,
                          1.0, 1.4142135623730951, 1.0, 1.4142135623730951};
    double pos[K_];
    for (int di = 0; di < 4; ++di) {
      double d = (double)(1 << di);
      for (int o = 0; o < 8; ++o) pos[di * 8 + o] = pv[o] * d;
    }
    double mean = 0; for (int k = 0; k < K_; ++k) mean += pos[k]; mean /= K_;
    double var = 0;  for (int k = 0; k < K_; ++k) { double dd = pos[k] - mean; var += dd * dd; }
    var /= (K_ - 1);
    double sd = sqrt(var);
    double pa[K_]; double m = -1e300;
    for (int k = 0; k < K_; ++k) {
      double r = pos[k] / ((sd + 1e-8) * 0.3);
      pa[k] = -(r * r);
      if (pa[k] > m) m = pa[k];
    }
    double es = 0; for (int k = 0; k < K_; ++k) { pa[k] = exp(pa[k] - m); es += pa[k]; }
    for (int k = 0; k < K_; ++k) ps.v[k] = (float)(0.01 * pa[k] / es);
  }

  aff_kernel<<<dim3(H_, B_), 128, 0, stream>>>(imgs, aff, ps);

  const int total4 = B_ * CM_ * PH_ * (PW_ / 4);
  pad_kernel<<<(total4 + 255) / 256, 256, 0, stream>>>(masks, P0, total4);

  const int nblk = B_ * 7 * (H_ / TR_);   // 896, XCD-pinned decode in kernel
  _Float16* s = P0;
  _Float16* d = P1;
  for (int it = 0; it < 9; ++it) {
    iter_kernel<1><<<nblk, 256, 0, stream>>>(s, aff, (void*)d);
    _Float16* tm = s; s = d; d = tm;
  }
  iter_kernel<0><<<nblk, 256, 0, stream>>>(s, aff, (void*)out);
}